// Round 8
// baseline (259.250 us; speedup 1.0000x reference)
//
#include <hip/hip_runtime.h>
#include <math.h>

#define KTOP 20
#define R_MAX 2048
#define SPLIT 2   // 512 blocks: 2 resident blocks/CU, one block-round, pipelined waves
#define ST 66     // LDS row stride in floats: 64 data + 2 pad

typedef float f4v __attribute__((ext_vector_type(4)));

// ---------------------------------------------------------------------------
// Kernel A: streaming pass, long-lived pipelined blocks.
// grid = B*SPLIT = 512 blocks x 256 threads (4 waves) -> exactly 2 blocks/CU,
// ALL resident: one block-round (vs 8 in r4), per-block preamble paid once.
// Each wave owns 256 rows = 8 half-tiles of 32 rows. Rolling 2-deep register
// pipeline (named bufs vA/vB, no runtime-indexed reg arrays): while half n is
// stored->LDS-staged->dotted, half n+1's 8 dwordx4 loads are in flight.
// Dot math / fp order identical to the verified r4 kernel.
// ---------------------------------------------------------------------------
static_assert(sizeof(float) * (4 * 32 * ST + 64) < 36 * 1024, "LDS budget");

__global__ __launch_bounds__(256, 2) void stream_sims(
    const float* __restrict__ x,
    const int* __restrict__ qrels,
    float* __restrict__ out,
    float* __restrict__ sims,
    float* __restrict__ dns,
    int R)
{
    __shared__ float s_q[64];
    __shared__ float s_tile[4][32 * ST];   // ~33.8 KB

    const int blk = blockIdx.x;
    const int b = blk >> 1;            // blk / SPLIT
    const int s = blk & (SPLIT - 1);
    const int t = threadIdx.x;
    const int qr = qrels[b];
    const long xbase = (long)b * R * 64;
    const long sbase = (long)b * R;

    // normalized query row (wave 0; once per block, now amortized over 1024 rows)
    if (t < 64) {
        float v = x[xbase + (long)qr * 64 + t];
        float ss = v * v;
#pragma unroll
        for (int m = 1; m < 64; m <<= 1) ss += __shfl_xor(ss, m, 64);
        s_q[t] = v / fmaxf(sqrtf(ss), 1e-12f);
    }
    __syncthreads();

    const int wid = t >> 6, lane = t & 63;
    const int g4 = lane >> 4, l16 = lane & 15;   // load mapping: 4 rows x 16 lanes
    const int h = lane >> 5, l32 = lane & 31;    // dot mapping: 2 lanes per row

    float4 q[8];
#pragma unroll
    for (int k = 0; k < 8; ++k) q[k] = *(const float4*)(s_q + h * 32 + k * 4);

    // this wave's rows: 256 consecutive, as 8 half-tiles of 32
    const int rowsPerBlock = R / SPLIT;            // 1024
    const int wrow0 = s * rowsPerBlock + wid * (rowsPerBlock / 4);
    float* lds = &s_tile[wid][0];

    float4 vA[8], vB[8];

    // ---- load a 32-row half-tile into regs (8 independent dwordx4) ----
    auto LOAD = [&](float4 (&v)[8], int rbase) {
#pragma unroll
        for (int j = 0; j < 8; ++j)
            v[j] = *(const float4*)(x + xbase + (long)(rbase + g4 + 4 * j) * 64 + l16 * 4);
    };

    // ---- consume a half-tile: NT-store out, stage LDS, dot, sims/dns ----
    auto PROCESS = [&](float4 (&v)[8], int rbase) {
#pragma unroll
        for (int j = 0; j < 8; ++j) {
            const int r = g4 + 4 * j;
            __builtin_nontemporal_store(*(const f4v*)&v[j],
                (f4v*)(out + xbase + (long)(rbase + r) * 64 + l16 * 4));
            float* p = lds + r * ST + l16 * 4;
            *(float2*)(p)     = make_float2(v[j].x, v[j].y);
            *(float2*)(p + 2) = make_float2(v[j].z, v[j].w);
        }
        float dot = 0.0f, ssv = 0.0f;
        const float* rp = lds + l32 * ST + h * 32;
#pragma unroll
        for (int k = 0; k < 16; ++k) {
            float2 rv = *(const float2*)(rp + 2 * k);
            const float* qf = (const float*)&q[k >> 1];
            float qa = qf[(2 * k) & 3], qb = qf[(2 * k + 1) & 3];
            dot += rv.x * qa + rv.y * qb;
            ssv += rv.x * rv.x + rv.y * rv.y;
        }
        dot += __shfl_xor(dot, 32, 64);
        ssv += __shfl_xor(ssv, 32, 64);
        if (h == 0) {
            const int row = rbase + l32;
            float dn = fmaxf(sqrtf(ssv), 1e-12f);
            sims[sbase + row] = (row == qr) ? -1.0f : dot / dn;
            dns[sbase + row] = dn;
        }
    };

    // ---- rolling pipeline over 8 half-tiles (4 pair-iterations) ----
    LOAD(vA, wrow0);                                    // half 0
    const int npairs = (rowsPerBlock / 4) / 64;         // 4
    for (int p = 0; p < npairs; ++p) {
        const int r0 = wrow0 + (2 * p) * 32;
        LOAD(vB, r0 + 32);                              // prefetch half 2p+1
        PROCESS(vA, r0);                                // consume half 2p
        if (p + 1 < npairs) LOAD(vA, r0 + 64);          // prefetch half 2p+2
        PROCESS(vB, r0 + 32);                           // consume half 2p+1
    }
    // NOTE: same-wave DS ops complete in issue order -> PROCESS(vB) ds_writes
    // cannot pass PROCESS(vA) ds_reads on the shared tile (r4-verified).
}

// ---------------------------------------------------------------------------
// Kernel B: selection + weighting + mixed-row write. grid = B x 256 threads.
// Verified logic (fp order identical to the round-1 passing kernel).
// ---------------------------------------------------------------------------
__global__ __launch_bounds__(256) void select_mix(
    const float* __restrict__ x,
    const int* __restrict__ qrels,
    const float* __restrict__ thr_raw,
    const float* __restrict__ str_raw,
    const float* __restrict__ wscale_p,
    const float* __restrict__ temp_p,
    const float* __restrict__ sims,
    const float* __restrict__ dns,
    float* __restrict__ out,
    int R)
{
    __shared__ float s_sims[R_MAX];
    __shared__ int   s_cand[R_MAX];
    __shared__ int   s_ncand;
    __shared__ float s_topv[KTOP];
    __shared__ int   s_topi[KTOP];
    __shared__ float s_dnsel[KTOP];
    __shared__ float s_adj[KTOP];
    __shared__ float s_strength;

    const int b = blockIdx.x;
    const int t = threadIdx.x;
    const int qr = qrels[b];
    const float threshold = 1.0f / (1.0f + expf(-thr_raw[0]));
    const long sbase = (long)b * R;
    const long xbase = (long)b * R * 64;

    if (t == 0) s_ncand = 0;
    __syncthreads();

    for (int i = t; i < R; i += 256) {
        float sv = sims[sbase + i];
        s_sims[i] = sv;
        if (sv > threshold) {
            int p = atomicAdd(&s_ncand, 1);
            s_cand[p] = i;
        }
    }
    __syncthreads();

    const int ncand = s_ncand;
    const int ksel = ncand < KTOP ? ncand : KTOP;

    if (t < 64) {
        float myv = 0.0f; int myi = 0;
        if (ncand > KTOP) {
            float lv[32]; int li[32];
#pragma unroll
            for (int j = 0; j < 32; ++j) {
                int i = t + 64 * j;
                if (i < ncand) { li[j] = s_cand[i]; lv[j] = s_sims[li[j]]; }
                else           { li[j] = 0x7fffffff; lv[j] = -INFINITY; }
            }
            for (int k = 0; k < KTOP; ++k) {
                float bv = -INFINITY; int bi = 0x7fffffff;
#pragma unroll
                for (int j = 0; j < 32; ++j)
                    if (lv[j] > bv || (lv[j] == bv && li[j] < bi)) { bv = lv[j]; bi = li[j]; }
#pragma unroll
                for (int m = 1; m < 64; m <<= 1) {
                    float v2 = __shfl_xor(bv, m, 64);
                    int   i2 = __shfl_xor(bi, m, 64);
                    if (v2 > bv || (v2 == bv && i2 < bi)) { bv = v2; bi = i2; }
                }
#pragma unroll
                for (int j = 0; j < 32; ++j) if (li[j] == bi) lv[j] = -INFINITY;
                if (t == k) { myv = bv; myi = bi; }
            }
        } else if (t < ksel) {
            myi = s_cand[t];
            myv = s_sims[myi];
        }
        if (t < ksel) {
            s_topv[t] = myv;
            s_topi[t] = myi;
            s_dnsel[t] = dns[sbase + myi];
        }
    }
    __syncthreads();

    if (t == 0) {
        float strength = (1.0f / (1.0f + expf(-str_raw[0]))) * 0.2f;
        float temp = fminf(fmaxf(temp_p[0], 0.1f), 10.0f);
        float wsc  = wscale_p[0];
        if (ksel > 0) {
            float m = -INFINITY;
            for (int k = 0; k < ksel; ++k) m = fmaxf(m, s_topv[k] / temp);
            float w[KTOP]; float wsum = 0.0f;
            for (int k = 0; k < ksel; ++k) { w[k] = expf(s_topv[k] / temp - m); wsum += w[k]; }
            float adj[KTOP]; float asum = 0.0f;
            for (int k = 0; k < ksel; ++k) {
                float tv = s_topv[k];
                float sw = 1.0f / (1.0f + expf(-(tv - threshold) * 10.0f));
                float a  = (w[k] / wsum) * sw * (1.0f + wsc * tv);
                adj[k] = a; asum += a;
            }
            for (int k = 0; k < ksel; ++k)
                s_adj[k] = (adj[k] / (asum + 1e-8f)) / s_dnsel[k];
        }
        s_strength = strength;
    }
    __syncthreads();

    if (t < 64 && ksel > 0) {
        const long qb = xbase + (long)qr * 64 + t;
        float qo = x[qb];
        float acc = 0.0f;
        for (int k = 0; k < ksel; ++k)
            acc += s_adj[k] * x[xbase + (long)s_topi[k] * 64 + t];
        float st = s_strength;
        out[qb] = (1.0f - st) * qo + st * acc;
    }
}

// ---------------------------------------------------------------------------
// Fallback: original verified fused kernel (odd shapes / no workspace).
// ---------------------------------------------------------------------------
__global__ __launch_bounds__(1024) void fused_enhancer(
    const float* __restrict__ x,
    const int* __restrict__ qrels,
    const float* __restrict__ thr_raw,
    const float* __restrict__ str_raw,
    const float* __restrict__ wscale_p,
    const float* __restrict__ temp_p,
    float* __restrict__ out, int R)
{
    __shared__ float s_q[64];
    __shared__ float s_sims[R_MAX];
    __shared__ float s_dn[R_MAX];
    __shared__ int   s_cand[R_MAX];
    __shared__ int   s_ncand;
    __shared__ float s_topv[KTOP];
    __shared__ int   s_topi[KTOP];
    __shared__ float s_adj[KTOP];
    __shared__ float s_strength;

    const int b = blockIdx.x;
    const int t = threadIdx.x;
    const int qr = qrels[b];
    const float threshold = 1.0f / (1.0f + expf(-thr_raw[0]));

    if (t == 0) s_ncand = 0;

    if (t < 64) {
        float v = x[((long)b * R + qr) * 64 + t];
        float ss = v * v;
#pragma unroll
        for (int m = 1; m < 64; m <<= 1) ss += __shfl_xor(ss, m, 64);
        s_q[t] = v / fmaxf(sqrtf(ss), 1e-12f);
    }
    __syncthreads();

    const int grp = t >> 4, l16 = t & 15;
    const float4 q4 = *(const float4*)(s_q + l16 * 4);
    const long xbase = (long)b * R * 64;
    for (int row = grp; row < R; row += 64) {
        long base = xbase + (long)row * 64 + l16 * 4;
        const float4 v = *(const float4*)(x + base);
        *(float4*)(out + base) = v;
        float dot = v.x * q4.x + v.y * q4.y + v.z * q4.z + v.w * q4.w;
        float ss  = v.x * v.x + v.y * v.y + v.z * v.z + v.w * v.w;
#pragma unroll
        for (int m = 1; m < 16; m <<= 1) {
            dot += __shfl_xor(dot, m, 64);
            ss  += __shfl_xor(ss,  m, 64);
        }
        if (l16 == 0) {
            float dn  = fmaxf(sqrtf(ss), 1e-12f);
            float sim = (row == qr) ? -1.0f : dot / dn;
            s_sims[row] = sim;
            s_dn[row]   = dn;
            if (sim > threshold) {
                int p = atomicAdd(&s_ncand, 1);
                s_cand[p] = row;
            }
        }
    }
    __syncthreads();

    const int ncand = s_ncand;
    const int ksel = ncand < KTOP ? ncand : KTOP;

    if (t < 64) {
        if (ncand > KTOP) {
            float lv[32]; int li[32];
#pragma unroll
            for (int j = 0; j < 32; ++j) {
                int i = t + 64 * j;
                if (i < ncand) { li[j] = s_cand[i]; lv[j] = s_sims[li[j]]; }
                else           { li[j] = 0x7fffffff; lv[j] = -INFINITY; }
            }
            for (int k = 0; k < KTOP; ++k) {
                float bv = -INFINITY; int bi = 0x7fffffff;
#pragma unroll
                for (int j = 0; j < 32; ++j) {
                    if (lv[j] > bv || (lv[j] == bv && li[j] < bi)) { bv = lv[j]; bi = li[j]; }
                }
#pragma unroll
                for (int m = 1; m < 64; m <<= 1) {
                    float v2 = __shfl_xor(bv, m, 64);
                    int   i2 = __shfl_xor(bi, m, 64);
                    if (v2 > bv || (v2 == bv && i2 < bi)) { bv = v2; bi = i2; }
                }
#pragma unroll
                for (int j = 0; j < 32; ++j) if (li[j] == bi) lv[j] = -INFINITY;
                if (t == 0) { s_topv[k] = bv; s_topi[k] = bi; }
            }
        } else if (t == 0) {
            for (int k = 0; k < ksel; ++k) {
                int idx = s_cand[k];
                s_topi[k] = idx;
                s_topv[k] = s_sims[idx];
            }
        }
    }

    if (t == 0) {
        float strength = (1.0f / (1.0f + expf(-str_raw[0]))) * 0.2f;
        float temp = fminf(fmaxf(temp_p[0], 0.1f), 10.0f);
        float wsc  = wscale_p[0];
        if (ksel > 0) {
            float m = -INFINITY;
            for (int k = 0; k < ksel; ++k) m = fmaxf(m, s_topv[k] / temp);
            float w[KTOP]; float wsum = 0.0f;
            for (int k = 0; k < ksel; ++k) { w[k] = expf(s_topv[k] / temp - m); wsum += w[k]; }
            float adj[KTOP]; float asum = 0.0f;
            for (int k = 0; k < ksel; ++k) {
                float tv = s_topv[k];
                float sw = 1.0f / (1.0f + expf(-(tv - threshold) * 10.0f));
                float a  = (w[k] / wsum) * sw * (1.0f + wsc * tv);
                adj[k] = a; asum += a;
            }
            for (int k = 0; k < ksel; ++k)
                s_adj[k] = (adj[k] / (asum + 1e-8f)) / s_dn[s_topi[k]];
        }
        s_strength = strength;
    }
    __syncthreads();

    if (t < 64 && ksel > 0) {
        long qb = ((long)b * R + qr) * 64 + t;
        float qo = x[qb];
        float acc = 0.0f;
        for (int k = 0; k < ksel; ++k)
            acc += s_adj[k] * x[((long)b * R + s_topi[k]) * 64 + t];
        float st = s_strength;
        out[qb] = (1.0f - st) * qo + st * acc;
    }
}

extern "C" void kernel_launch(void* const* d_in, const int* in_sizes, int n_in,
                              void* d_out, int out_size, void* d_ws, size_t ws_size,
                              hipStream_t stream) {
    const float* x      = (const float*)d_in[0];
    const int*   qrels  = (const int*)d_in[1];
    const float* thr    = (const float*)d_in[2];
    const float* str    = (const float*)d_in[3];
    const float* wscale = (const float*)d_in[4];
    const float* temp   = (const float*)d_in[5];
    float* out = (float*)d_out;

    const int B = in_sizes[1];
    const int D = 64;
    const int R = in_sizes[0] / (B * D);
    (void)D;

    const size_t need = (size_t)B * R * 2 * sizeof(float);
    // pipelined path: each block covers R/SPLIT rows; each of its 4 waves
    // covers (R/SPLIT)/4 rows in half-tiles of 32, paired -> need /256 整除
    if (d_ws != nullptr && ws_size >= need && R <= R_MAX &&
        (R % (SPLIT * 4 * 64)) == 0 && ((R / SPLIT / 4) % 64) == 0) {
        float* sims = (float*)d_ws;
        float* dns  = sims + (size_t)B * R;
        stream_sims<<<B * SPLIT, 256, 0, stream>>>(x, qrels, out, sims, dns, R);
        select_mix<<<B, 256, 0, stream>>>(x, qrels, thr, str, wscale, temp,
                                          sims, dns, out, R);
    } else {
        fused_enhancer<<<B, 1024, 0, stream>>>(x, qrels, thr, str, wscale, temp, out, R);
    }
}